// Round 3
// baseline (92.357 us; speedup 1.0000x reference)
//
#include <hip/hip_runtime.h>

#define BEVN 100
#define NB 8
#define NC 512
#define FH 88
#define FW 176
#define HWSZ (FH * FW)          // 15488 floats = 61,952 B per (b,c) slice
#define NQUAD (BEVN * BEVN / 4) // 2500 cell-quads per slice

// One block per (b,c). Stage slice in LDS + per-row y-projection table
// (validity & 1/3 folded into weights). Each thread handles QUADS of cells
// (quads never straddle rows: 100 % 4 == 0; cell base = 4*p), sharing invz +
// y-table reads. X-corner pairs are read from a common clamped base so the
// compiler merges them into ds_read2_b32 (halves LDS instruction count).
__global__ __launch_bounds__(1024, 8)
void vt_kernel(const float* __restrict__ img,
               const float* __restrict__ intr,
               const int* __restrict__ p_imw,
               const int* __restrict__ p_imh,
               float* __restrict__ out)
{
    __shared__ float  lds[HWSZ];
    __shared__ float4 ytab[BEVN * 3];   // per (row,plane): {wy0/3, wy1/3, rowbase0, rowbase1}

    const int bc  = blockIdx.x;         // b*512 + c
    const int b   = bc >> 9;
    const int tid = (int)threadIdx.x;

    // ---- stage [88][176] f32 slice into LDS, coalesced float4 ----
    {
        const float4* __restrict__ s4 = (const float4*)(img + (size_t)bc * HWSZ);
        float4* l4 = (float4*)lds;
        #pragma unroll
        for (int t = 0; t < 4; ++t) {
            const int idx = tid + t * 1024;
            if (idx < HWSZ / 4) l4[idx] = s4[idx];
        }
    }

    const float fx  = intr[b * 9 + 0];
    const float cxv = intr[b * 9 + 2];
    const float fy  = intr[b * 9 + 4];
    const float cyv = intr[b * 9 + 5];
    const float wsc = (float)FW / (float)p_imw[0];   // 0.25
    const float hsc = (float)FH / (float)p_imh[0];   // 0.25

    // ---- per-row y table: depends only on (b, row, plane). 300 entries ----
    if (tid < BEVN * 3) {
        const int   i  = tid / 3;
        const int   k  = tid - 3 * i;
        const float z  = 0.125f + 0.5f * (float)i;
        const float iz = 1.0f / z;                    // precise, one-time
        const float yk = (k == 0) ? -1.0f : ((k == 1) ? 0.5f : 2.0f);
        const float yp = fmaf(fy * yk * iz + cyv, hsc, -0.5f);
        const float yf = floorf(yp);
        const int   y0 = (int)yf;
        float wy1 = yp - yf;
        float wy0 = 1.0f - wy1;
        wy0 = ((unsigned)y0 < (unsigned)FH) ? wy0 : 0.0f;
        wy1 = ((unsigned)(y0 + 1) < (unsigned)FH) ? wy1 : 0.0f;
        const int yb0 = min(max(y0, 0), FH - 1) * FW;
        const int yb1 = min(max(y0 + 1, 0), FH - 1) * FW;
        float4 e;
        e.x = wy0 * (1.0f / 3.0f);
        e.y = wy1 * (1.0f / 3.0f);
        e.z = __int_as_float(yb0);
        e.w = __int_as_float(yb1);
        ytab[tid] = e;
    }

    __syncthreads();

    // x-projection constants: xpix = a_j * invz + bx, a_j = axb + axs*j
    const float axs = 0.5f * fx * wsc;
    const float axb = -24.875f * fx * wsc;
    const float bx  = fmaf(cxv, wsc, -0.5f);

    float* __restrict__ op = out + (size_t)bc * (BEVN * BEVN);

    for (int p = tid; p < NQUAD; p += 1024) {
        const int i  = p / 25;               // BEV row
        const int jq = p - 25 * i;           // quad index in row; j base = 4*jq
        const float z    = fmaf(0.5f, (float)i, 0.125f);
        const float invz = __builtin_amdgcn_rcpf(z);

        int   xb[4];
        float w0[4], w1[4];
        #pragma unroll
        for (int e = 0; e < 4; ++e) {
            const float aj   = fmaf((float)(4 * jq + e), axs, axb);
            const float xpix = fmaf(aj, invz, bx);
            const float f    = floorf(xpix);
            const int   x0   = (int)f;
            float wx1 = xpix - f;
            float wx0 = 1.0f - wx1;
            wx0 = ((unsigned)x0 < (unsigned)FW) ? wx0 : 0.0f;
            wx1 = ((unsigned)(x0 + 1) < (unsigned)FW) ? wx1 : 0.0f;
            const int xbe = min(max(x0, 0), FW - 2);
            const int d   = x0 - xbe;        // -?..0..1: <0 means x0 clamped up, >0 clamped down
            w0[e] = (d == 0) ? wx0 : ((d < 0) ? wx1 : 0.0f);
            w1[e] = (d == 0) ? wx1 : ((d < 0) ? 0.0f : wx0);
            xb[e] = xbe;
        }

        float4 res;
        const float wsum = (w0[0] + w1[0]) + (w0[1] + w1[1])
                         + (w0[2] + w1[2]) + (w0[3] + w1[3]);
        if (wsum == 0.0f) {
            res.x = res.y = res.z = res.w = 0.0f;   // whole quad OOB in x
        } else {
            float acc[4] = {0.0f, 0.0f, 0.0f, 0.0f};
            #pragma unroll
            for (int k = 0; k < 3; ++k) {
                const float4 e4  = ytab[i * 3 + k];
                const int    yb0 = __float_as_int(e4.z);
                const int    yb1 = __float_as_int(e4.w);
                #pragma unroll
                for (int e = 0; e < 4; ++e) {
                    const float* r0 = lds + (yb0 + xb[e]);
                    const float* r1 = lds + (yb1 + xb[e]);
                    const float v00 = r0[0], v01 = r0[1];   // -> ds_read2_b32
                    const float v10 = r1[0], v11 = r1[1];   // -> ds_read2_b32
                    const float h0 = fmaf(w1[e], v01, w0[e] * v00);
                    const float h1 = fmaf(w1[e], v11, w0[e] * v10);
                    acc[e] = fmaf(e4.x, h0, acc[e]);
                    acc[e] = fmaf(e4.y, h1, acc[e]);
                }
            }
            res.x = acc[0]; res.y = acc[1]; res.z = acc[2]; res.w = acc[3];
        }
        *(float4*)(op + 4 * p) = res;        // cell base = 4*p, 16B aligned
    }
}

extern "C" void kernel_launch(void* const* d_in, const int* in_sizes, int n_in,
                              void* d_out, int out_size, void* d_ws, size_t ws_size,
                              hipStream_t stream) {
    const float* img  = (const float*)d_in[0];
    const float* intr = (const float*)d_in[1];
    const int*   imw  = (const int*)d_in[2];
    const int*   imh  = (const int*)d_in[3];
    float*       out  = (float*)d_out;

    dim3 grid(NB * NC);   // one block per (b,c)
    dim3 block(1024);
    hipLaunchKernelGGL(vt_kernel, grid, block, 0, stream,
                       img, intr, imw, imh, out);
}

// Round 4
// 91.262 us; speedup vs baseline: 1.0120x; 1.0120x over previous
//
#include <hip/hip_runtime.h>

#define BEVN 100
#define NB 8
#define NC 512
#define FH 88
#define FW 176
#define HWSZ (FH * FW)          // 15488 pixels per channel slice
#define NG4  (HWSZ / 4)         // 3872 groups of 4 pixels
#define NPAIR (BEVN * BEVN / 2) // 5000 cell-pairs

// Block = (b, channel-pair). Stage TWO channel slices packed as bf16 pairs
// (one u32 per pixel) -> every gathered dword serves both channels, halving
// LDS gather traffic per output. Projection math + ytab shared across the
// pair too. Cells processed in pairs (share invz / ytab, float2 stores).
__device__ __forceinline__ unsigned bf16rne(float f) {
    const unsigned b = __float_as_uint(f);
    return (b + 0x7fffu + ((b >> 16) & 1u)) >> 16;   // round-nearest-even
}
__device__ __forceinline__ float lo16f(unsigned u) { return __uint_as_float(u << 16); }
__device__ __forceinline__ float hi16f(unsigned u) { return __uint_as_float(u & 0xffff0000u); }

__global__ __launch_bounds__(1024, 8)
void vt_kernel(const float* __restrict__ img,
               const float* __restrict__ intr,
               const int* __restrict__ p_imw,
               const int* __restrict__ p_imh,
               float* __restrict__ out)
{
    __shared__ unsigned lds[HWSZ];      // per-pixel {bf16 ch0 | bf16 ch1<<16}
    __shared__ float4   ytab[BEVN * 3]; // per (row,plane): {wy0/3, wy1/3, rowbase0, rowbase1}

    const int blk = blockIdx.x;         // b*256 + cpair
    const int b   = blk >> 8;
    const int c0  = (blk & 255) * 2;
    const int bc0 = b * NC + c0;
    const int tid = (int)threadIdx.x;

    // ---- stage 2 channel slices, packed bf16, coalesced f32x4 reads ----
    {
        const float4* __restrict__ s0 = (const float4*)(img + (size_t)bc0 * HWSZ);
        const float4* __restrict__ s1 = s0 + NG4;    // next channel (contiguous)
        uint4* l4 = (uint4*)lds;
        for (int idx = tid; idx < NG4; idx += 1024) {
            const float4 a  = s0[idx];
            const float4 bb = s1[idx];
            uint4 u;
            u.x = bf16rne(a.x) | (bf16rne(bb.x) << 16);
            u.y = bf16rne(a.y) | (bf16rne(bb.y) << 16);
            u.z = bf16rne(a.z) | (bf16rne(bb.z) << 16);
            u.w = bf16rne(a.w) | (bf16rne(bb.w) << 16);
            l4[idx] = u;
        }
    }

    const float fx  = intr[b * 9 + 0];
    const float cxv = intr[b * 9 + 2];
    const float fy  = intr[b * 9 + 4];
    const float cyv = intr[b * 9 + 5];
    const float wsc = (float)FW / (float)p_imw[0];   // 0.25
    const float hsc = (float)FH / (float)p_imh[0];   // 0.25

    // ---- per-row y table (row,plane): validity & 1/3 folded into weights ----
    if (tid < BEVN * 3) {
        const int   i  = tid / 3;
        const int   k  = tid - 3 * i;
        const float z  = 0.125f + 0.5f * (float)i;
        const float iz = 1.0f / z;
        const float yk = (k == 0) ? -1.0f : ((k == 1) ? 0.5f : 2.0f);
        const float yp = fmaf(fy * yk * iz + cyv, hsc, -0.5f);
        const float yf = floorf(yp);
        const int   y0 = (int)yf;
        float wy1 = yp - yf;
        float wy0 = 1.0f - wy1;
        wy0 = ((unsigned)y0 < (unsigned)FH) ? wy0 : 0.0f;
        wy1 = ((unsigned)(y0 + 1) < (unsigned)FH) ? wy1 : 0.0f;
        const int yb0 = min(max(y0, 0), FH - 1) * FW;
        const int yb1 = min(max(y0 + 1, 0), FH - 1) * FW;
        float4 e;
        e.x = wy0 * (1.0f / 3.0f);
        e.y = wy1 * (1.0f / 3.0f);
        e.z = __int_as_float(yb0);
        e.w = __int_as_float(yb1);
        ytab[tid] = e;
    }

    __syncthreads();

    // x-projection: xpix = a_j * invz + bx, a_j = axb + axs*j
    const float axs = 0.5f * fx * wsc;
    const float axb = -24.875f * fx * wsc;
    const float bx  = fmaf(cxv, wsc, -0.5f);

    float* __restrict__ op0 = out + (size_t)bc0 * (BEVN * BEVN);
    float* __restrict__ op1 = op0 + (BEVN * BEVN);

    for (int p = tid; p < NPAIR; p += 1024) {
        const int i  = p / 50;               // BEV row
        const int jp = p - 50 * i;           // pair index in row
        const float z    = fmaf(0.5f, (float)i, 0.125f);
        const float invz = __builtin_amdgcn_rcpf(z);

        int   xb[2];
        float w0[2], w1[2];
        #pragma unroll
        for (int e = 0; e < 2; ++e) {
            const float aj   = fmaf((float)(2 * jp + e), axs, axb);
            const float xpix = fmaf(aj, invz, bx);
            const float f    = floorf(xpix);
            const int   x0   = (int)f;
            float wx1 = xpix - f;
            float wx0 = 1.0f - wx1;
            wx0 = ((unsigned)x0 < (unsigned)FW) ? wx0 : 0.0f;
            wx1 = ((unsigned)(x0 + 1) < (unsigned)FW) ? wx1 : 0.0f;
            const int xbe = min(max(x0, 0), FW - 2);
            const int d   = x0 - xbe;        // 0: normal; <0: x0 clamped up; >0: clamped down
            w0[e] = (d == 0) ? wx0 : ((d < 0) ? wx1 : 0.0f);
            w1[e] = (d == 0) ? wx1 : ((d < 0) ? 0.0f : wx0);
            xb[e] = xbe;
        }

        float2 rA, rB;
        const float wsum = (w0[0] + w1[0]) + (w0[1] + w1[1]);
        if (wsum == 0.0f) {
            rA.x = rA.y = rB.x = rB.y = 0.0f;  // whole pair OOB in x (wave-coherent skip)
        } else {
            float accA[2] = {0.0f, 0.0f};
            float accB[2] = {0.0f, 0.0f};
            #pragma unroll
            for (int k = 0; k < 3; ++k) {
                const float4 e4  = ytab[i * 3 + k];
                const int    yb0 = __float_as_int(e4.z);
                const int    yb1 = __float_as_int(e4.w);
                #pragma unroll
                for (int e = 0; e < 2; ++e) {
                    const unsigned* r0 = lds + (yb0 + xb[e]);
                    const unsigned* r1 = lds + (yb1 + xb[e]);
                    const unsigned u00 = r0[0], u01 = r0[1];   // -> ds_read2_b32
                    const unsigned u10 = r1[0], u11 = r1[1];   // -> ds_read2_b32
                    // channel 0 (low half)
                    const float h0a = fmaf(w1[e], lo16f(u01), w0[e] * lo16f(u00));
                    const float h1a = fmaf(w1[e], lo16f(u11), w0[e] * lo16f(u10));
                    accA[e] = fmaf(e4.x, h0a, accA[e]);
                    accA[e] = fmaf(e4.y, h1a, accA[e]);
                    // channel 1 (high half)
                    const float h0b = fmaf(w1[e], hi16f(u01), w0[e] * hi16f(u00));
                    const float h1b = fmaf(w1[e], hi16f(u11), w0[e] * hi16f(u10));
                    accB[e] = fmaf(e4.x, h0b, accB[e]);
                    accB[e] = fmaf(e4.y, h1b, accB[e]);
                }
            }
            rA.x = accA[0]; rA.y = accA[1];
            rB.x = accB[0]; rB.y = accB[1];
        }
        *(float2*)(op0 + 2 * p) = rA;
        *(float2*)(op1 + 2 * p) = rB;
    }
}

extern "C" void kernel_launch(void* const* d_in, const int* in_sizes, int n_in,
                              void* d_out, int out_size, void* d_ws, size_t ws_size,
                              hipStream_t stream) {
    const float* img  = (const float*)d_in[0];
    const float* intr = (const float*)d_in[1];
    const int*   imw  = (const int*)d_in[2];
    const int*   imh  = (const int*)d_in[3];
    float*       out  = (float*)d_out;

    dim3 grid(NB * NC / 2);   // one block per (b, channel-pair)
    dim3 block(1024);
    hipLaunchKernelGGL(vt_kernel, grid, block, 0, stream,
                       img, intr, imw, imh, out);
}